// Round 3
// baseline (1006.299 us; speedup 1.0000x reference)
//
#include <hip/hip_runtime.h>
#include <math.h>
#include <stdint.h>

// ---------------------------------------------------------------------------
// QuantizedLinear: out = x @ quantize(w)^T + bias
//   quantize(w) = clip(round(w/(mean|w|+eps)*h), -h, h),  h=(2^1.58-1)/2
//   Ternary trick: qw in {-h,0,+h} -> store t in {-1,0,+1} as EXACT bf16,
//   scale by h (fp32) in GEMM epilogue. Only x suffers bf16 rounding.
// Shapes: x[16384,4096] (M,K) fp32, w[4096,4096] (N,K) fp32, bias[4096],
//         out[16384,4096] fp32.  NT GEMM (both operands K-contiguous).
//
// R5: pipelined fragment reads (read phase p+1's frags during phase p's MFMA).
//   R4 read frags in the SAME phase that consumed them: per phase the wave's
//   MFMA start was gated on its ds_reads clearing the shared LDS port, and
//   the end barrier propagated the slowest wave -> reads serialized with
//   MFMA. Model: sum(reads_cyc + 515) per K-tile = 4364 cyc vs 2061 MFMA
//   -> 47% cap (measured 46.5%). Now each phase issues NEXT phase's reads
//   before its MFMA cluster; compiler emits counted lgkmcnt automatically;
//   4 barriers/K-tile (was 8); explicit vmcnt(4) only (dep invisible to
//   compiler). Frags: faA double-buffered (A0/A1 roles fixed), fbB0/fbB1
//   single (E4 loads fbB0 post-MFMA in P4; WAR via program order).
//   Ring (verified): P1 stage (kt+1).B1->Nx, P2 (kt+1).A1->Nx, P3
//   (kt+2).A0->Cb, P4 (kt+2).B0->Cb; vmcnt(4) after P2 (retires kt+1.A0/B0
//   -> P3 may read Nx.A0) and after P4 (retires kt+1.B1/A1).
// ---------------------------------------------------------------------------

#define MDIM 16384
#define NDIM 4096
#define KDIM 4096

// ---------------- reduction: sum |w| in double ----------------
__global__ void absmean_reduce(const float4* __restrict__ w4,
                               double* __restrict__ gsum, int n4) {
  int tid = blockIdx.x * blockDim.x + threadIdx.x;
  int stride = gridDim.x * blockDim.x;
  double s = 0.0;
  for (int i = tid; i < n4; i += stride) {
    float4 v = w4[i];
    s += (double)fabsf(v.x) + (double)fabsf(v.y) +
         (double)fabsf(v.z) + (double)fabsf(v.w);
  }
  for (int off = 32; off > 0; off >>= 1) s += __shfl_down(s, off, 64);
  __shared__ double partial[4];
  int ln = threadIdx.x & 63, wv = threadIdx.x >> 6;
  if (ln == 0) partial[wv] = s;
  __syncthreads();
  if (threadIdx.x == 0) {
    double t = partial[0] + partial[1] + partial[2] + partial[3];
    atomicAdd(gsum, t);
  }
}

// ---------------- quantize w -> ternary bf16 {-1,0,+1} ----------------
__device__ __forceinline__ unsigned short tern_bf16(float w, float g, float h) {
  float q = rintf(w / g * h);             // RNE, matches jnp.round
  q = fminf(fmaxf(q, -1.0f), 1.0f);       // {-2..2} -> {-1,0,1}
  return (unsigned short)(__float_as_uint(q) >> 16);  // ±1.0/±0.0 exact bf16
}

__global__ void quantize_w(const float4* __restrict__ w4,
                           const double* __restrict__ gsum,
                           ushort4* __restrict__ wq, int n4, float halfF) {
  const float gamma = (float)(*gsum * (1.0 / 16777216.0)) + 1e-8f;
  int tid = blockIdx.x * blockDim.x + threadIdx.x;
  int stride = gridDim.x * blockDim.x;
  for (int i = tid; i < n4; i += stride) {
    float4 v = w4[i];
    ushort4 o;
    o.x = tern_bf16(v.x, gamma, halfF);
    o.y = tern_bf16(v.y, gamma, halfF);
    o.z = tern_bf16(v.z, gamma, halfF);
    o.w = tern_bf16(v.w, gamma, halfF);
    wq[i] = o;
  }
}

// ---------------- convert x fp32 -> bf16 (RNE) ----------------
__device__ __forceinline__ unsigned bf16_rne(float f) {
  unsigned u = __float_as_uint(f);
  return (u + 0x7FFFu + ((u >> 16) & 1u)) >> 16;
}
__device__ __forceinline__ unsigned pack2(float lo, float hi) {
  return bf16_rne(lo) | (bf16_rne(hi) << 16);
}

__global__ void cvt_x(const float4* __restrict__ x4, uint4* __restrict__ xb,
                      int n8) {
  int tid = blockIdx.x * blockDim.x + threadIdx.x;
  int stride = gridDim.x * blockDim.x;
  for (int i = tid; i < n8; i += stride) {
    float4 a = x4[2 * i];
    float4 b = x4[2 * i + 1];
    uint4 o;
    o.x = pack2(a.x, a.y);
    o.y = pack2(a.z, a.w);
    o.z = pack2(b.x, b.y);
    o.w = pack2(b.z, b.w);
    xb[i] = o;
  }
}

// ---------------- GEMM: 256x256 tile, BK=64, pipelined 4-phase ------------
typedef __attribute__((ext_vector_type(8))) short bf16x8;  // 8 bf16 = 4 VGPRs
typedef __attribute__((ext_vector_type(4))) float f32x4;

#define BM 256
#define BN 256
#define BK 64
#define NTK (KDIM / BK)  // 64 K-tiles

__device__ __forceinline__ void async16(const short* g, short* l) {
  __builtin_amdgcn_global_load_lds(
      (const __attribute__((address_space(1))) unsigned int*)g,
      (__attribute__((address_space(3))) unsigned int*)l, 16, 0, 0);
}

#define SB __builtin_amdgcn_sched_barrier(0)

__global__ __launch_bounds__(512, 2) void gemm_tern_256(
    const short* __restrict__ A,    // [M][K] bf16 bits (x)
    const short* __restrict__ Bw,   // [N][K] bf16 ternary (qw/h)
    const float* __restrict__ bias, // [N]
    float* __restrict__ out,        // [M][N] fp32
    float scale) {
  // LDS: buf(2) x { A-half0, A-half1, B-half0, B-half1 }, each 128x64 bf16.
  // shorts: half = 8192, B area = +16384, buf stride = 32768; 128 KiB total.
  extern __shared__ short lds[];

  const int tid = threadIdx.x;
  const int wv = tid >> 6;   // 0..7
  const int ln = tid & 63;
  const int wr = wv >> 2;    // 0..1  (M group)
  const int wc = wv & 3;     // 0..3  (N group)
  const int l15 = ln & 15;
  const int lq = ln >> 4;    // 0..3
  const int l7 = ln & 7;

  // XCD-bijective block swizzle: nwg=1024, 8 XCDs, 128 blocks each.
  const int orig = blockIdx.x;
  const int wg = ((orig & 7) << 7) | (orig >> 3);
  const int bm = (wg >> 4) * BM;
  const int bn = (wg & 15) * BN;

  // ---- staging addressing (2 global_load_lds per half-tile per wave) ----
  // LDS slot (row,c) holds global chunk c^(row&7) (bank-conflict-free, R2).
  const int g8 = ln >> 3;
  const int sw = (l7 ^ (g8 & 7)) << 3;  // swizzled global chunk offset
  const int grp0 = wv * 2, grp1 = wv * 2 + 1;
  const short* aP0 = A + (size_t)(bm + grp0 * 8 + g8) * KDIM + sw;
  const short* aP1 = A + (size_t)(bm + grp1 * 8 + g8) * KDIM + sw;
  const short* bP0 = Bw + (size_t)(bn + grp0 * 8 + g8) * KDIM + sw;
  const short* bP1 = Bw + (size_t)(bn + grp1 * 8 + g8) * KDIM + sw;
  const int d0 = grp0 * 512, d1 = grp1 * 512;  // LDS dst (shorts) within half

  // ---- ds_read lane offsets (shorts) ----
  const int c0 = (lq ^ l7) << 3;         // chunk slot, k-slice 0
  const int c1 = ((4 + lq) ^ l7) << 3;   // chunk slot, k-slice 1
  const int aRow = (wr * 64 + l15) * 64;
  const int bRow = 16384 + (wc * 32 + l15) * 64;

  f32x4 acc[2][2][4][2] = {};            // [mh][nh][m][n] -> 128 AGPRs
  bf16x8 faA_a[4][2];                    // A0-half frags (role fixed)
  bf16x8 faA_b[4][2];                    // A1-half frags (role fixed)
  bf16x8 fbB0[2][2], fbB1[2][2];         // B-half frags

#define KOF(s) ((size_t)(((s) < NTK) ? (s) : 0) * BK)
#define STAGE_A(DST, H, S)                                 \
  do {                                                     \
    const size_t koA_ = KOF(S) + (size_t)(H) * 128 * KDIM; \
    async16(aP0 + koA_, (DST) + (H) * 8192 + d0);          \
    async16(aP1 + koA_, (DST) + (H) * 8192 + d1);          \
  } while (0)
#define STAGE_B(DST, H, S)                                 \
  do {                                                     \
    const size_t koB_ = KOF(S) + (size_t)(H) * 128 * KDIM; \
    async16(bP0 + koB_, (DST) + 16384 + (H) * 8192 + d0);  \
    async16(bP1 + koB_, (DST) + 16384 + (H) * 8192 + d1);  \
  } while (0)

#define LOAD_FA(DST, B0_, B1_, OFF)                             \
  _Pragma("unroll") for (int m = 0; m < 4; ++m) {               \
    DST[m][0] = *(const bf16x8*)((B0_) + (OFF) + m * 1024);     \
    DST[m][1] = *(const bf16x8*)((B1_) + (OFF) + m * 1024);     \
  }
#define LOAD_FB(DST, B0_, B1_, OFF)                             \
  _Pragma("unroll") for (int n = 0; n < 2; ++n) {               \
    DST[n][0] = *(const bf16x8*)((B0_) + (OFF) + n * 1024);     \
    DST[n][1] = *(const bf16x8*)((B1_) + (OFF) + n * 1024);     \
  }

#define MFMAQ(MH, NH, FA, FB)                                        \
  do {                                                               \
    __builtin_amdgcn_s_setprio(1);                                   \
    _Pragma("unroll") for (int m = 0; m < 4; ++m)                    \
        _Pragma("unroll") for (int n = 0; n < 2; ++n) {              \
      acc[MH][NH][m][n] = __builtin_amdgcn_mfma_f32_16x16x32_bf16(   \
          FA[m][0], FB[n][0], acc[MH][NH][m][n], 0, 0, 0);           \
      acc[MH][NH][m][n] = __builtin_amdgcn_mfma_f32_16x16x32_bf16(   \
          FA[m][1], FB[n][1], acc[MH][NH][m][n], 0, 0, 0);           \
    }                                                                \
    __builtin_amdgcn_s_setprio(0);                                   \
  } while (0)

  // ---- prologue: tile0 all 4 halves + tile1 A0/B0; then frag preload ----
  {
    short* b0 = lds;
    short* b1 = lds + 32768;
    STAGE_A(b0, 0, 0);
    STAGE_B(b0, 0, 0);
    STAGE_B(b0, 1, 0);
    STAGE_A(b0, 1, 0);
    STAGE_A(b1, 0, 1);
    STAGE_B(b1, 0, 1);
  }
  asm volatile("s_waitcnt vmcnt(4)" ::: "memory");  // tile0 in; tile1 A0/B0 fly
  SB;
  __builtin_amdgcn_s_barrier();
  SB;
  LOAD_FA(faA_a, lds + aRow + c0, lds + aRow + c1, 0);   // tile0.A0
  LOAD_FB(fbB0, lds + bRow + c0, lds + bRow + c1, 0);    // tile0.B0

  for (int kt = 0; kt < NTK; ++kt) {
    const int curS = (kt & 1) << 15;
    const short* Cb = lds + curS;            // current buffer
    const short* Nx = lds + (curS ^ 32768);  // next buffer
    short* Cw = lds + curS;
    short* Nw = lds + (curS ^ 32768);
    const short* aC0 = Cb + aRow + c0;
    const short* aC1 = Cb + aRow + c1;
    const short* bC0 = Cb + bRow + c0;
    const short* bC1 = Cb + bRow + c1;
    const short* aN0 = Nx + aRow + c0;
    const short* aN1 = Nx + aRow + c1;
    const short* bN0 = Nx + bRow + c0;
    const short* bN1 = Nx + bRow + c1;

    // -- P1 (0,0): prefetch fbB1<-Cb.B1 | stage (kt+1).B1 | MFMA faA_a x fbB0
    SB;
    __builtin_amdgcn_s_barrier();
    SB;
    LOAD_FB(fbB1, bC0, bC1, 8192);
    STAGE_B(Nw, 1, kt + 1);
    SB;
    MFMAQ(0, 0, faA_a, fbB0);

    // -- P2 (0,1): prefetch faA_b<-Cb.A1 | stage (kt+1).A1 | MFMA faA_a x fbB1
    SB;
    __builtin_amdgcn_s_barrier();
    SB;
    LOAD_FA(faA_b, aC0, aC1, 8192);
    STAGE_A(Nw, 1, kt + 1);
    SB;
    MFMAQ(0, 1, faA_a, fbB1);
    SB;
    asm volatile("s_waitcnt vmcnt(4)" ::: "memory");  // (kt+1).A0/B0 landed

    // -- P3 (1,1): prefetch faA_a<-Nx.A0 | stage (kt+2).A0->Cb | MFMA faA_b x fbB1
    SB;
    __builtin_amdgcn_s_barrier();
    SB;
    LOAD_FA(faA_a, aN0, aN1, 0);
    STAGE_A(Cw, 0, kt + 2);
    SB;
    MFMAQ(1, 1, faA_b, fbB1);

    // -- P4 (1,0): stage (kt+2).B0->Cb | MFMA faA_b x fbB0 | post: fbB0<-Nx.B0
    SB;
    __builtin_amdgcn_s_barrier();
    SB;
    STAGE_B(Cw, 0, kt + 2);
    SB;
    MFMAQ(1, 0, faA_b, fbB0);
    SB;
    LOAD_FB(fbB0, bN0, bN1, 0);
    SB;
    asm volatile("s_waitcnt vmcnt(4)" ::: "memory");  // (kt+1).B1/A1 landed
  }

  // ---- epilogue: C/D layout col=ln&15, row=(ln>>4)*4+r (m89-verified) ----
  const int colb = bn + wc * 32 + l15;
  const int rowb = bm + wr * 64 + (lq << 2);
#pragma unroll
  for (int nh = 0; nh < 2; ++nh)
#pragma unroll
    for (int n = 0; n < 2; ++n) {
      const int col = colb + nh * 128 + n * 16;
      const float bj = bias[col];
#pragma unroll
      for (int mh = 0; mh < 2; ++mh)
#pragma unroll
        for (int m = 0; m < 4; ++m) {
          const int row = rowb + mh * 128 + m * 16;
#pragma unroll
          for (int r = 0; r < 4; ++r)
            out[(size_t)(row + r) * NDIM + col] =
                fmaf(acc[mh][nh][m][n][r], scale, bj);
        }
    }
}

// ---------------- launch ----------------
extern "C" void kernel_launch(void* const* d_in, const int* in_sizes, int n_in,
                              void* d_out, int out_size, void* d_ws,
                              size_t ws_size, hipStream_t stream) {
  const float* x = (const float*)d_in[0];     // [16384*4096]
  const float* w = (const float*)d_in[1];     // [4096*4096]
  const float* bias = (const float*)d_in[2];  // [4096]
  float* out = (float*)d_out;

  char* ws = (char*)d_ws;
  double* gsum = (double*)ws;                                // 8 B
  short* xb = (short*)(ws + 256);                            // 134 MB
  short* wq = (short*)(ws + 256 + (size_t)MDIM * KDIM * 2);  // 33.5 MB

  const float kHalfF = (float)((pow(2.0, 1.58) - 1.0) * 0.5);  // 0.99484926f

  static bool attr_done = false;
  if (!attr_done) {
    (void)hipFuncSetAttribute((const void*)gemm_tern_256,
                              hipFuncAttributeMaxDynamicSharedMemorySize,
                              131072);
    attr_done = true;
  }

  hipMemsetAsync(gsum, 0, sizeof(double), stream);

  const int nW4 = (NDIM * KDIM) / 4;
  absmean_reduce<<<1024, 256, 0, stream>>>((const float4*)w, gsum, nW4);

  quantize_w<<<4096, 256, 0, stream>>>((const float4*)w, gsum, (ushort4*)wq,
                                       nW4, kHalfF);

  const int nX8 = (MDIM * KDIM) / 8;
  cvt_x<<<8192, 256, 0, stream>>>((const float4*)x, (uint4*)xb, nX8);

  dim3 grid((MDIM / BM) * (NDIM / BN));  // 64 * 16 = 1024 blocks
  gemm_tern_256<<<grid, 512, 131072, stream>>>(xb, wq, bias, out, kHalfF);
}